// Round 12
// baseline (129.727 us; speedup 1.0000x reference)
//
#include <hip/hip_runtime.h>
#include <math.h>

typedef _Float16 f16;
typedef _Float16 f16x4 __attribute__((ext_vector_type(4)));
typedef _Float16 f16x8 __attribute__((ext_vector_type(8)));
typedef __bf16 bf16x2 __attribute__((ext_vector_type(2)));
typedef __bf16 bf16x4 __attribute__((ext_vector_type(4)));
typedef __bf16 bf16x4a8 __attribute__((ext_vector_type(4), aligned(8)));
typedef short s16x4 __attribute__((ext_vector_type(4)));
typedef float f32x4 __attribute__((ext_vector_type(4)));

#define MFMA_F16(a, b, c)  __builtin_amdgcn_mfma_f32_16x16x32_f16(a, b, c, 0, 0, 0)
#define MFMA_BF16_K16(a, b, c) __builtin_amdgcn_mfma_f32_16x16x16bf16_1k(a, b, c, 0, 0, 0)

#define VSS 12160  // panels per shift = 32 bg * 38 hp * 10

static __device__ inline f16x8 cvt8(const float* p) {
    const float4* p4 = (const float4*)p;
    float4 u0 = p4[0], u1 = p4[1];
    f16x8 r;
    r[0] = (f16)u0.x; r[1] = (f16)u0.y; r[2] = (f16)u0.z; r[3] = (f16)u0.w;
    r[4] = (f16)u1.x; r[5] = (f16)u1.y; r[6] = (f16)u1.z; r[7] = (f16)u1.w;
    return r;
}

// ---------------------------------------------------------------------------
// Fused producer (unchanged from R11). Blocks 0..1215: (b,g,hp) rows ->
// Q,K,V via f16 MFMA; block 1216 builds relp.
// Layouts: Qb f16 [pos][g*128+oc]; Kb f16 [b][g][hp][wp][c];
//   V4 bf16, 4 wp-shifted panel copies: V4[s][bg][hp][panel p][c][wp4].
// ---------------------------------------------------------------------------
__global__ __launch_bounds__(256) void produce_kernel(
    const float* __restrict__ x,
    const float* __restrict__ wq, const float* __restrict__ bq,
    const float* __restrict__ wk, const float* __restrict__ bk,
    const float* __restrict__ wv, const float* __restrict__ bv,
    const float* __restrict__ rel_h, const float* __restrict__ rel_w,
    f16* __restrict__ Qb, f16* __restrict__ Kb,
    __bf16* __restrict__ V4, f16* __restrict__ relp) {
    int bid = blockIdx.x;
    int t = threadIdx.x;

    if (bid == 1216) {  // rel' table: key=(gp*7+kh)*8+kw, channel c
        for (int idx = t; idx < 448 * 32; idx += 256) {
            int c = idx & 31, key = idx >> 5;
            int kw = key & 7, ghk = key >> 3;
            int gp = (ghk * 37) >> 8;
            int kh = ghk - gp * 7;
            float v = 0.f;
            if (kw < 7)
                v = (c < 16) ? rel_h[c * 56 + gp * 7 + kh]
                             : rel_w[(c - 16) * 56 + gp * 7 + kw];
            relp[idx] = (f16)v;
        }
        return;
    }

    int hp = bid % 38, g = (bid / 38) & 7, b = bid / 304;
    bool hin = (hp >= 3 && hp < 35);
    size_t kvbase = (size_t)(b * 8 + g);
    size_t rowp = (kvbase * 38 + hp) * 10;  // panel row (within one shift)

    if (!hin) {  // pure-bias row (h padding)
        for (int idx = t; idx < 38 * 32; idx += 256) {
            int wp = idx >> 5, c = idx & 31;
            Kb[((kvbase * 38 + hp) * 38 + wp) * 32 + c] = (f16)bk[g * 32 + c];
        }
        for (int idx = t; idx < 4 * 40 * 32; idx += 256) {  // s, w', c
            int c = idx & 31, w = (idx >> 5) % 40, s = (idx >> 5) / 40;
            int wp = s + w;  // slot (s, w>>2, w&3)
            __bf16 val = (wp <= 37) ? (__bf16)bv[g * 32 + c] : (__bf16)0.f;
            V4[((size_t)s * VSS + rowp + (w >> 2)) * 128 + c * 4 + (w & 3)] = val;
        }
        return;
    }

    int h = hp - 3;
    __shared__ __align__(16) f16 xTl[32 * 40];  // [w][ic], stride 40

    {   // stage x^T (each thread one float4 along w)
        int ic = t >> 3, w = (t & 7) * 4;
        float4 xv = *(const float4*)(x + (((size_t)b * 256 + g * 32 + ic) * 32 + h) * 32 + w);
        xTl[(w + 0) * 40 + ic] = (f16)xv.x;
        xTl[(w + 1) * 40 + ic] = (f16)xv.y;
        xTl[(w + 2) * 40 + ic] = (f16)xv.z;
        xTl[(w + 3) * 40 + ic] = (f16)xv.w;
    }
    __syncthreads();

    int l15 = t & 15, quad = (t >> 4) & 3, wave = t >> 6;

    f16x8 xf0 = *(const f16x8*)(xTl + l15 * 40 + quad * 8);
    f16x8 xf1 = *(const f16x8*)(xTl + (16 + l15) * 40 + quad * 8);

    // ---- Q: A=wq rows=oc; wave covers oc-tiles wave*2 + {0,1} ----
#pragma unroll
    for (int i = 0; i < 2; ++i) {
        int mq = wave * 2 + i;  // oc-tile 0..7
        f16x8 wf = cvt8(wq + ((size_t)g * 128 + mq * 16 + l15) * 32 + quad * 8);
        float4 b4 = *(const float4*)(bq + g * 128 + mq * 16 + quad * 4);
#pragma unroll
        for (int Nt = 0; Nt < 2; ++Nt) {
            f32x4 d = {0.f, 0.f, 0.f, 0.f};
            d = MFMA_F16(wf, Nt ? xf1 : xf0, d);
            f16x4 q4;
            q4[0] = (f16)(d[0] + b4.x); q4[1] = (f16)(d[1] + b4.y);
            q4[2] = (f16)(d[2] + b4.z); q4[3] = (f16)(d[3] + b4.w);
            int w = Nt * 16 + l15;
            *(f16x4*)(Qb + (size_t)((b * 32 + h) * 32 + w) * 1024 + g * 128 + mq * 16 + quad * 4) = q4;
        }
    }

    if (wave < 2) {
        // ---- K: A=wk rows=c; wave = c-tile ----
        f16x8 wf = cvt8(wk + ((size_t)g * 32 + wave * 16 + l15) * 32 + quad * 8);
        float4 b4 = *(const float4*)(bk + g * 32 + wave * 16 + quad * 4);
#pragma unroll
        for (int Nt = 0; Nt < 2; ++Nt) {
            f32x4 d = {0.f, 0.f, 0.f, 0.f};
            d = MFMA_F16(wf, Nt ? xf1 : xf0, d);
            f16x4 k4;
            k4[0] = (f16)(d[0] + b4.x); k4[1] = (f16)(d[1] + b4.y);
            k4[2] = (f16)(d[2] + b4.z); k4[3] = (f16)(d[3] + b4.w);
            int wp = Nt * 16 + l15 + 3;
            *(f16x4*)(Kb + ((kvbase * 38 + hp) * 38 + wp) * 32 + wave * 16 + quad * 4) = k4;
        }
    } else {
        // ---- V: A=x^T rows=wp; wave-2 = c-tile; write 4 shifted panel copies
        int Nt = wave - 2;
        f16x8 wf = cvt8(wv + ((size_t)g * 32 + Nt * 16 + l15) * 32 + quad * 8);
        float bias = bv[g * 32 + Nt * 16 + l15];
        int c = Nt * 16 + l15;
#pragma unroll
        for (int Mt = 0; Mt < 2; ++Mt) {
            f32x4 d = {0.f, 0.f, 0.f, 0.f};
            d = MFMA_F16(Mt ? xf1 : xf0, wf, d);
            __bf16 v0 = (__bf16)(d[0] + bias), v1 = (__bf16)(d[1] + bias);
            __bf16 v2 = (__bf16)(d[2] + bias), v3 = (__bf16)(d[3] + bias);
            int p0 = Mt * 4 + quad;  // wp0 mod 4 == 3 for all shifts
            __bf16* P0 = V4 + ((size_t)0 * VSS + rowp + p0) * 128 + c * 4;
            __bf16* P1 = V4 + ((size_t)1 * VSS + rowp + p0) * 128 + c * 4;
            __bf16* P2 = V4 + ((size_t)2 * VSS + rowp + p0) * 128 + c * 4;
            __bf16* P3 = V4 + ((size_t)3 * VSS + rowp + p0) * 128 + c * 4;
            { bf16x4a8 q; q[0] = v0; q[1] = v1; q[2] = v2; q[3] = v3; *(bf16x4a8*)P3 = q; }
            { P2[1] = v0; bf16x2 m; m[0] = v1; m[1] = v2; *(bf16x2*)(P2 + 2) = m; P2[128] = v3; }
            { bf16x2 m; m[0] = v0; m[1] = v1; *(bf16x2*)(P1 + 2) = m;
              bf16x2 n; n[0] = v2; n[1] = v3; *(bf16x2*)(P1 + 128) = n; }
            { P0[3] = v0; bf16x2 m; m[0] = v1; m[1] = v2; *(bf16x2*)(P0 + 128) = m; P0[130] = v3; }
        }
    }

    // ---- wp borders (bias) + zero tails ----
    for (int idx = t; idx < 192; idx += 256) {  // Kb borders
        int wi = idx >> 5, c = idx & 31;
        int wp = (wi < 3) ? wi : (32 + wi);  // {0,1,2,35,36,37}
        Kb[((kvbase * 38 + hp) * 38 + wp) * 32 + c] = (f16)bk[g * 32 + c];
    }
    for (int idx = t; idx < 4 * 6 * 32; idx += 256) {  // V4 borders, per shift
        int c = idx & 31, wi = (idx >> 5) % 6, s = (idx >> 5) / 6;
        int wp = (wi < 3) ? wi : (32 + wi);
        if (wp >= s) {
            int w = wp - s;
            V4[((size_t)s * VSS + rowp + (w >> 2)) * 128 + c * 4 + (w & 3)] =
                (__bf16)bv[g * 32 + c];
        }
    }
    for (int idx = t; idx < 4 * 5 * 32; idx += 256) {  // V4 zero tails wp>=38
        int c = idx & 31, j = (idx >> 5) % 5, s = (idx >> 5) / 5;
        int w = 35 + j;  // slot w' -> wp = s + w
        if (s + w >= 38)
            V4[((size_t)s * VSS + rowp + (w >> 2)) * 128 + c * 4 + (w & 3)] = (__bf16)0.f;
    }
}

// ---------------------------------------------------------------------------
// MFMA attention, x-paired split-K: each wave handles TWO positions (x0,x0+1)
// sharing the 8-row union of their K/V windows — kb and V fragments loaded
// once serve pos0 at kh=r and pos1 at kh=r-1; rel fragment reused via a
// 1-deep register pipeline (rpPrev). Loads/chunk: 8 kb + 7 rp + 16 V = 31
// (was 56 for two positions). Zero-LDS main loop; split-K combine via LDS.
// __launch_bounds__(128,3): VGPR cap ~170 (est. usage ~120; (128,8) caused
// catastrophic spills in R9 — watch WRITE_SIZE).
// ---------------------------------------------------------------------------
__global__ __launch_bounds__(128, 3) void attn_kernel(
    const f16* __restrict__ Qb, const f16* __restrict__ Kb,
    const __bf16* __restrict__ V4, const f16* __restrict__ relp,
    float* __restrict__ out) {
    int bid = blockIdx.x;
    int t = threadIdx.x;
    int wvi = t >> 6;
    int pp = (bid & 7) * 256 + (bid >> 3);  // XCD swizzle over 2048 pairs
    int y = pp & 31, xp = (pp >> 5) & 15, b = pp >> 9;
    int x0 = xp * 2;
    int pid0 = (b * 32 + x0) * 32 + y;  // pos1 = pid0 + 32

    __shared__ __align__(16) float accS[64 * 40];  // wave1 partials

    int lane = t & 63;
    int l15 = lane & 15, quad = lane >> 4, kwl = lane & 7, p8 = (lane >> 3) & 1;
    bool oddq = (quad & 1);

    // Q fragments for both positions (B-role: n=qi=l15, k=c=quad*8+j)
    f16x8 qf0[2], qf1[2];
    {
        const f16* qp = Qb + (size_t)pid0 * 1024;
        qf0[0] = *(const f16x8*)(qp + l15 * 32 + quad * 8);
        qf0[1] = *(const f16x8*)(qp + (16 + l15) * 32 + quad * 8);
        qp += 32 * 1024;
        qf1[0] = *(const f16x8*)(qp + l15 * 32 + quad * 8);
        qf1[1] = *(const f16x8*)(qp + (16 + l15) * 32 + quad * 8);
    }

    float fsum[2][2] = {{0.f, 0.f}, {0.f, 0.f}};  // [pos][Mt]
    f32x4 acc[2][2][2];  // [pos][ct][Mt]
#pragma unroll
    for (int p = 0; p < 2; ++p)
#pragma unroll
        for (int ct = 0; ct < 2; ++ct)
#pragma unroll
            for (int m = 0; m < 2; ++m) acc[p][ct][m] = (f32x4){0.f, 0.f, 0.f, 0.f};

    int yk = y + kwl;
    if (yk > 37) yk = 37;  // masked row: clamp (finite garbage, exp->0)
    size_t vshift = (size_t)(y & 3) * VSS;

    for (int chunk = wvi * 2; chunk < wvi * 2 + 2; ++chunk) {
        int gpr = chunk * 2 + p8;           // key-row group (K/relp)
        int gpv = chunk * 2 + (quad >> 1);  // V-fragment group
        const f16* kbp = Kb + ((((size_t)(b * 8 + gpr) * 38 + x0) * 38 + yk) << 5) + quad * 8;
        const f16* rpp = relp + ((size_t)(gpr * 56 + kwl) << 5) + quad * 8;
        const __bf16* vp0 = V4 +
            ((vshift + ((size_t)(b * 8 + gpv) * 38 + x0) * 10 + (y >> 2) + (quad & 1)) << 7) +
            l15 * 4;
        const __bf16* vp1 = vp0 + 64;  // c + 16
        f16x8 rpPrev;
#pragma unroll
        for (int r = 0; r < 8; ++r) {
            f16x8 kb = *(const f16x8*)kbp;  kbp += 38 * 32;
            s16x4 vf0 = *(const s16x4*)vp0;  vp0 += 1280;
            s16x4 vf1 = *(const s16x4*)vp1;  vp1 += 1280;
            if (r >= 1) {  // pos1, kh = r-1, rel row r-1 (pipelined)
                f16x8 kbr = kb + rpPrev;
#pragma unroll
                for (int Mt = 0; Mt < 2; ++Mt) {
                    f32x4 d = {0.f, 0.f, 0.f, 0.f};
                    d = MFMA_F16(kbr, qf1[Mt], d);
                    float e0 = __expf(d[0]);
                    float e1 = __expf(d[1]);
                    float e2 = __expf(d[2]);
                    float e3 = oddq ? 0.f : __expf(d[3]);
                    fsum[1][Mt] += (e0 + e1) + (e2 + e3);
                    bf16x4 pb;
                    pb[0] = (__bf16)e0; pb[1] = (__bf16)e1;
                    pb[2] = (__bf16)e2; pb[3] = (__bf16)e3;
                    s16x4 pbi = __builtin_bit_cast(s16x4, pb);
                    acc[1][0][Mt] = MFMA_BF16_K16(vf0, pbi, acc[1][0][Mt]);
                    acc[1][1][Mt] = MFMA_BF16_K16(vf1, pbi, acc[1][1][Mt]);
                }
            }
            if (r < 7) {   // pos0, kh = r
                f16x8 rp = *(const f16x8*)rpp;  rpp += 256;
                f16x8 kbr = kb + rp;
#pragma unroll
                for (int Mt = 0; Mt < 2; ++Mt) {
                    f32x4 d = {0.f, 0.f, 0.f, 0.f};
                    d = MFMA_F16(kbr, qf0[Mt], d);
                    float e0 = __expf(d[0]);
                    float e1 = __expf(d[1]);
                    float e2 = __expf(d[2]);
                    float e3 = oddq ? 0.f : __expf(d[3]);
                    fsum[0][Mt] += (e0 + e1) + (e2 + e3);
                    bf16x4 pb;
                    pb[0] = (__bf16)e0; pb[1] = (__bf16)e1;
                    pb[2] = (__bf16)e2; pb[3] = (__bf16)e3;
                    s16x4 pbi = __builtin_bit_cast(s16x4, pb);
                    acc[0][0][Mt] = MFMA_BF16_K16(vf0, pbi, acc[0][0][Mt]);
                    acc[0][1][Mt] = MFMA_BF16_K16(vf1, pbi, acc[0][1][Mt]);
                }
                rpPrev = rp;
            }
        }
    }

    // ---- intra-wave fsum reduce across quads ----
#pragma unroll
    for (int p = 0; p < 2; ++p)
#pragma unroll
        for (int m = 0; m < 2; ++m) {
            fsum[p][m] += __shfl_xor(fsum[p][m], 16);
            fsum[p][m] += __shfl_xor(fsum[p][m], 32);
        }

    // ---- cross-wave combine ----
    if (wvi == 1) {
        float* sp = accS + lane * 40;
#pragma unroll
        for (int p = 0; p < 2; ++p)
#pragma unroll
            for (int ct = 0; ct < 2; ++ct)
#pragma unroll
                for (int m = 0; m < 2; ++m)
                    *(f32x4*)(sp + (p * 4 + ct * 2 + m) * 4) = acc[p][ct][m];
        sp[32] = fsum[0][0]; sp[33] = fsum[0][1];
        sp[34] = fsum[1][0]; sp[35] = fsum[1][1];
    }
    __syncthreads();
    if (wvi == 1) return;

    {
        const float* sp = accS + lane * 40;
#pragma unroll
        for (int p = 0; p < 2; ++p)
#pragma unroll
            for (int ct = 0; ct < 2; ++ct)
#pragma unroll
                for (int m = 0; m < 2; ++m)
                    acc[p][ct][m] += *(const f32x4*)(sp + (p * 4 + ct * 2 + m) * 4);
        fsum[0][0] += sp[32]; fsum[0][1] += sp[33];
        fsum[1][0] += sp[34]; fsum[1][1] += sp[35];
    }

    // ---- epilogue per position: normalize, head-sum over l15&3, store ----
#pragma unroll
    for (int p = 0; p < 2; ++p) {
        float inv[2] = {1.0f / fsum[p][0], 1.0f / fsum[p][1]};
        int x = x0 + p;
#pragma unroll
        for (int Mt = 0; Mt < 2; ++Mt)
#pragma unroll
            for (int ct = 0; ct < 2; ++ct) {
                float v[4];
#pragma unroll
                for (int r = 0; r < 4; ++r) {
                    v[r] = acc[p][ct][Mt][r] * inv[Mt];
                    v[r] += __shfl_xor(v[r], 1);
                    v[r] += __shfl_xor(v[r], 2);
                }
                if ((l15 & 3) == 0) {
                    int g = Mt * 4 + (l15 >> 2);
                    float4 o4 = {v[0], v[1], v[2], v[3]};
                    *(float4*)(out + ((((size_t)(b * 8 + g) * 32 + x) * 32 + y) << 5) +
                               ct * 16 + quad * 4) = o4;
                }
            }
    }
}

// ---------------------------------------------------------------------------
extern "C" void kernel_launch(void* const* d_in, const int* in_sizes, int n_in,
                              void* d_out, int out_size, void* d_ws, size_t ws_size,
                              hipStream_t stream) {
    const float* x     = (const float*)d_in[0];
    const float* wq    = (const float*)d_in[1];
    const float* bq    = (const float*)d_in[2];
    const float* wk    = (const float*)d_in[3];
    const float* bk    = (const float*)d_in[4];
    const float* wv    = (const float*)d_in[5];
    const float* bv    = (const float*)d_in[6];
    const float* rel_h = (const float*)d_in[7];
    const float* rel_w = (const float*)d_in[8];
    float* out = (float*)d_out;

    // ws layout (bytes):
    //   Qb  f16 : 4096*1024*2            = 8,388,608
    //   Kb  f16 : 4*8*38*38*32*2         = 2,957,312
    //   V4  bf16: 4 shifts * 12160*128*2 = 12,451,840
    //   relp f16: 448*32*2               = 28,672
    unsigned char* ws = (unsigned char*)d_ws;
    f16*    Qb   = (f16*)ws;
    f16*    Kb   = (f16*)(ws + 8388608);
    __bf16* V4   = (__bf16*)(ws + 8388608 + 2957312);
    f16*    relp = (f16*)(ws + 8388608 + 2957312 + 12451840);

    hipLaunchKernelGGL(produce_kernel, dim3(1217), dim3(256), 0, stream,
                       x, wq, bq, wk, bk, wv, bv, rel_h, rel_w, Qb, Kb, V4, relp);
    hipLaunchKernelGGL(attn_kernel, dim3(2048), dim3(128), 0, stream,
                       Qb, Kb, V4, relp, out);
}

// Round 13
// 118.584 us; speedup vs baseline: 1.0940x; 1.0940x over previous
//
#include <hip/hip_runtime.h>
#include <math.h>

typedef _Float16 f16;
typedef _Float16 f16x4 __attribute__((ext_vector_type(4)));
typedef _Float16 f16x8 __attribute__((ext_vector_type(8)));
typedef __bf16 bf16x4 __attribute__((ext_vector_type(4)));
typedef __bf16 bf16x4a8 __attribute__((ext_vector_type(4), aligned(8)));
typedef short s16x4 __attribute__((ext_vector_type(4)));
typedef float f32x4 __attribute__((ext_vector_type(4)));

#define MFMA_F16(a, b, c)  __builtin_amdgcn_mfma_f32_16x16x32_f16(a, b, c, 0, 0, 0)
#define MFMA_BF16_K16(a, b, c) __builtin_amdgcn_mfma_f32_16x16x16bf16_1k(a, b, c, 0, 0, 0)

#define VSS 12160  // panels per shift = 32 bg * 38 hp * 10

static __device__ inline f16x8 cvt8(const float* p) {
    const float4* p4 = (const float4*)p;
    float4 u0 = p4[0], u1 = p4[1];
    f16x8 r;
    r[0] = (f16)u0.x; r[1] = (f16)u0.y; r[2] = (f16)u0.z; r[3] = (f16)u0.w;
    r[4] = (f16)u1.x; r[5] = (f16)u1.y; r[6] = (f16)u1.z; r[7] = (f16)u1.w;
    return r;
}

// ---------------------------------------------------------------------------
// Fused producer. Blocks 0..1215: (b,g,hp) rows -> Q,K,V via f16 MFMA;
// block 1216 builds relp.
// V path: MFMA results -> LDS vt[c][wp] (fp32, borders/zeros included) ->
// cooperative coalesced 8-B bf16x4 stores of all 4 shifted panel copies
// (replaces ~2300 scattered 2/4-B global stores per block).
// Layouts: Qb f16 [pos][g*128+oc]; Kb f16 [b][g][hp][wp][c];
//   V4 bf16, 4 wp-shifted panel copies: V4[s][bg][hp][panel p][c][wp4]
//   (slot (s,p,o) holds wp = s + 4p + o).
// ---------------------------------------------------------------------------
__global__ __launch_bounds__(256) void produce_kernel(
    const float* __restrict__ x,
    const float* __restrict__ wq, const float* __restrict__ bq,
    const float* __restrict__ wk, const float* __restrict__ bk,
    const float* __restrict__ wv, const float* __restrict__ bv,
    const float* __restrict__ rel_h, const float* __restrict__ rel_w,
    f16* __restrict__ Qb, f16* __restrict__ Kb,
    __bf16* __restrict__ V4, f16* __restrict__ relp) {
    int bid = blockIdx.x;
    int t = threadIdx.x;

    if (bid == 1216) {  // rel' table: key=(gp*7+kh)*8+kw, channel c
        for (int idx = t; idx < 448 * 32; idx += 256) {
            int c = idx & 31, key = idx >> 5;
            int kw = key & 7, ghk = key >> 3;
            int gp = (ghk * 37) >> 8;
            int kh = ghk - gp * 7;
            float v = 0.f;
            if (kw < 7)
                v = (c < 16) ? rel_h[c * 56 + gp * 7 + kh]
                             : rel_w[(c - 16) * 56 + gp * 7 + kw];
            relp[idx] = (f16)v;
        }
        return;
    }

    int hp = bid % 38, g = (bid / 38) & 7, b = bid / 304;
    bool hin = (hp >= 3 && hp < 35);
    size_t kvbase = (size_t)(b * 8 + g);
    size_t rowp = (kvbase * 38 + hp) * 10;  // panel row (within one shift)

    if (!hin) {  // pure-bias row (h padding)
        for (int idx = t; idx < 38 * 32; idx += 256) {
            int wp = idx >> 5, c = idx & 31;
            Kb[((kvbase * 38 + hp) * 38 + wp) * 32 + c] = (f16)bk[g * 32 + c];
        }
        for (int idx = t; idx < 4 * 40 * 32; idx += 256) {  // s, w', c
            int c = idx & 31, w = (idx >> 5) % 40, s = (idx >> 5) / 40;
            int wp = s + w;  // slot (s, w>>2, w&3)
            __bf16 val = (wp <= 37) ? (__bf16)bv[g * 32 + c] : (__bf16)0.f;
            V4[((size_t)s * VSS + rowp + (w >> 2)) * 128 + c * 4 + (w & 3)] = val;
        }
        return;
    }

    int h = hp - 3;
    __shared__ __align__(16) f16 xTl[32 * 40];   // [w][ic], stride 40
    __shared__ float vt[32 * 44];                // [c][wp], wp 0..43 (>=38 zero)

    {   // stage x^T (each thread one float4 along w)
        int ic = t >> 3, w = (t & 7) * 4;
        float4 xv = *(const float4*)(x + (((size_t)b * 256 + g * 32 + ic) * 32 + h) * 32 + w);
        xTl[(w + 0) * 40 + ic] = (f16)xv.x;
        xTl[(w + 1) * 40 + ic] = (f16)xv.y;
        xTl[(w + 2) * 40 + ic] = (f16)xv.z;
        xTl[(w + 3) * 40 + ic] = (f16)xv.w;
    }
    // vt borders: wp {0,1,2,35,36,37} = bias; wp 38..43 = 0   (384 items)
    for (int idx = t; idx < 384; idx += 256) {
        int c = idx & 31, wi = idx >> 5;  // wi 0..11
        float bb = bv[g * 32 + c];
        int wp = (wi < 3) ? wi : ((wi < 6) ? (32 + wi) : (32 + wi));
        if (wi < 3) vt[c * 44 + wi] = bb;                 // 0,1,2
        else if (wi < 6) vt[c * 44 + 32 + wi] = bb;       // 35,36,37
        else vt[c * 44 + 32 + wi] = 0.f;                  // 38..43
        (void)wp;
    }
    __syncthreads();

    int l15 = t & 15, quad = (t >> 4) & 3, wave = t >> 6;

    f16x8 xf0 = *(const f16x8*)(xTl + l15 * 40 + quad * 8);
    f16x8 xf1 = *(const f16x8*)(xTl + (16 + l15) * 40 + quad * 8);

    // ---- Q: A=wq rows=oc; wave covers oc-tiles wave*2 + {0,1} ----
#pragma unroll
    for (int i = 0; i < 2; ++i) {
        int mq = wave * 2 + i;  // oc-tile 0..7
        f16x8 wf = cvt8(wq + ((size_t)g * 128 + mq * 16 + l15) * 32 + quad * 8);
        float4 b4 = *(const float4*)(bq + g * 128 + mq * 16 + quad * 4);
#pragma unroll
        for (int Nt = 0; Nt < 2; ++Nt) {
            f32x4 d = {0.f, 0.f, 0.f, 0.f};
            d = MFMA_F16(wf, Nt ? xf1 : xf0, d);
            f16x4 q4;
            q4[0] = (f16)(d[0] + b4.x); q4[1] = (f16)(d[1] + b4.y);
            q4[2] = (f16)(d[2] + b4.z); q4[3] = (f16)(d[3] + b4.w);
            int w = Nt * 16 + l15;
            *(f16x4*)(Qb + (size_t)((b * 32 + h) * 32 + w) * 1024 + g * 128 + mq * 16 + quad * 4) = q4;
        }
    }

    if (wave < 2) {
        // ---- K: A=wk rows=c; wave = c-tile ----
        f16x8 wf = cvt8(wk + ((size_t)g * 32 + wave * 16 + l15) * 32 + quad * 8);
        float4 b4 = *(const float4*)(bk + g * 32 + wave * 16 + quad * 4);
#pragma unroll
        for (int Nt = 0; Nt < 2; ++Nt) {
            f32x4 d = {0.f, 0.f, 0.f, 0.f};
            d = MFMA_F16(wf, Nt ? xf1 : xf0, d);
            f16x4 k4;
            k4[0] = (f16)(d[0] + b4.x); k4[1] = (f16)(d[1] + b4.y);
            k4[2] = (f16)(d[2] + b4.z); k4[3] = (f16)(d[3] + b4.w);
            int wp = Nt * 16 + l15 + 3;
            *(f16x4*)(Kb + ((kvbase * 38 + hp) * 38 + wp) * 32 + wave * 16 + quad * 4) = k4;
        }
    } else {
        // ---- V: A=x^T rows=wp; wave-2 = c-tile; results -> LDS vt ----
        int Nt = wave - 2;
        f16x8 wf = cvt8(wv + ((size_t)g * 32 + Nt * 16 + l15) * 32 + quad * 8);
        float bias = bv[g * 32 + Nt * 16 + l15];
        int c = Nt * 16 + l15;
#pragma unroll
        for (int Mt = 0; Mt < 2; ++Mt) {
            f32x4 d = {0.f, 0.f, 0.f, 0.f};
            d = MFMA_F16(Mt ? xf1 : xf0, wf, d);
            int wp0 = Mt * 16 + quad * 4 + 3;
            vt[c * 44 + wp0 + 0] = d[0] + bias;
            vt[c * 44 + wp0 + 1] = d[1] + bias;
            vt[c * 44 + wp0 + 2] = d[2] + bias;
            vt[c * 44 + wp0 + 3] = d[3] + bias;
        }
    }

    // ---- Kb wp borders (bias) ----
    for (int idx = t; idx < 192; idx += 256) {
        int wi = idx >> 5, c = idx & 31;
        int wp = (wi < 3) ? wi : (32 + wi);  // {0,1,2,35,36,37}
        Kb[((kvbase * 38 + hp) * 38 + wp) * 32 + c] = (f16)bk[g * 32 + c];
    }
    __syncthreads();

    // ---- cooperative V4 write: 4 shifts x 10 panels x 32 c, coalesced ----
    for (int idx = t; idx < 1280; idx += 256) {
        int c = idx & 31;
        int p = (idx >> 5) % 10;
        int s = (idx >> 5) / 10;
        const float* src = vt + c * 44 + s + p * 4;
        bf16x4a8 q;
        q[0] = (__bf16)src[0]; q[1] = (__bf16)src[1];
        q[2] = (__bf16)src[2]; q[3] = (__bf16)src[3];
        *(bf16x4a8*)(V4 + ((size_t)s * VSS + rowp + p) * 128 + c * 4) = q;
    }
}

// ---------------------------------------------------------------------------
// MFMA attention (R11 structure, verbatim): split-K, 2 waves/position,
// zero-LDS main loop, register-resident P (transposed scores), V4 panel
// loads, cross-wave combine via LDS. __launch_bounds__(128,4).
// ---------------------------------------------------------------------------
__global__ __launch_bounds__(128, 4) void attn_kernel(
    const f16* __restrict__ Qb, const f16* __restrict__ Kb,
    const __bf16* __restrict__ V4, const f16* __restrict__ relp,
    float* __restrict__ out) {
    int bid = blockIdx.x;
    int t = threadIdx.x;
    int wvi = t >> 6;
    int pid = (bid & 7) * 512 + (bid >> 3);  // XCD swizzle, one position/block
    int y = pid & 31, x = (pid >> 5) & 31, b = pid >> 10;

    __shared__ __align__(16) float accS[64 * 20];  // wave1 partials, stride 20

    int lane = t & 63;
    int l15 = lane & 15, quad = lane >> 4, kwl = lane & 7, p8 = (lane >> 3) & 1;
    bool oddq = (quad & 1);

    // Q fragments (B-role: n=qi=l15, k=c=quad*8+j)
    f16x8 qf[2];
    {
        const f16* qp = Qb + (size_t)pid * 1024;
        qf[0] = *(const f16x8*)(qp + l15 * 32 + quad * 8);
        qf[1] = *(const f16x8*)(qp + (16 + l15) * 32 + quad * 8);
    }

    float fsumT[2] = {0.f, 0.f};
    f32x4 acc[2][2];  // [ct][Mt]: O^T rows c=ct*16+quad*4+r, cols qi tile Mt
#pragma unroll
    for (int ct = 0; ct < 2; ++ct)
#pragma unroll
        for (int m = 0; m < 2; ++m) acc[ct][m] = (f32x4){0.f, 0.f, 0.f, 0.f};

    int yk = y + kwl;
    if (yk > 37) yk = 37;  // masked row: clamp (finite garbage, exp->0)
    size_t vshift = (size_t)(y & 3) * VSS;

    for (int chunk = wvi * 2; chunk < wvi * 2 + 2; ++chunk) {
        int gpr = chunk * 2 + p8;           // this lane's key-row group (K/relp)
        int gpv = chunk * 2 + (quad >> 1);  // this lane's V-fragment group
        const f16* kbp = Kb + ((((size_t)(b * 8 + gpr) * 38 + x) * 38 + yk) << 5) + quad * 8;
        const f16* rpp = relp + ((size_t)(gpr * 56 + kwl) << 5) + quad * 8;
        const __bf16* vp0 = V4 +
            ((vshift + ((size_t)(b * 8 + gpv) * 38 + x) * 10 + (y >> 2) + (quad & 1)) << 7) +
            l15 * 4;
        const __bf16* vp1 = vp0 + 64;  // c + 16
#pragma unroll
        for (int kh = 0; kh < 7; ++kh) {
            f16x8 kb = *(const f16x8*)kbp;  kbp += 38 * 32;
            f16x8 rp = *(const f16x8*)rpp;  rpp += 256;
            kb += rp;  // K' = K + rel'
            s16x4 vf0 = *(const s16x4*)vp0;  vp0 += 1280;
            s16x4 vf1 = *(const s16x4*)vp1;  vp1 += 1280;
#pragma unroll
            for (int Mt = 0; Mt < 2; ++Mt) {
                f32x4 d = {0.f, 0.f, 0.f, 0.f};
                d = MFMA_F16(kb, qf[Mt], d);  // S^T: rows=keys, cols=qi
                float e0 = __expf(d[0]);
                float e1 = __expf(d[1]);
                float e2 = __expf(d[2]);
                float e3 = oddq ? 0.f : __expf(d[3]);  // kw=7 mask
                fsumT[Mt] += (e0 + e1) + (e2 + e3);
                bf16x4 pb;
                pb[0] = (__bf16)e0; pb[1] = (__bf16)e1;
                pb[2] = (__bf16)e2; pb[3] = (__bf16)e3;
                s16x4 pbi = __builtin_bit_cast(s16x4, pb);
                acc[0][Mt] = MFMA_BF16_K16(vf0, pbi, acc[0][Mt]);
                acc[1][Mt] = MFMA_BF16_K16(vf1, pbi, acc[1][Mt]);
            }
        }
    }

    // ---- intra-wave fsum reduce across quads ----
#pragma unroll
    for (int m = 0; m < 2; ++m) {
        fsumT[m] += __shfl_xor(fsumT[m], 16);
        fsumT[m] += __shfl_xor(fsumT[m], 32);
    }

    // ---- cross-wave combine ----
    if (wvi == 1) {
        float* sp = accS + lane * 20;
        *(f32x4*)(sp + 0)  = acc[0][0];
        *(f32x4*)(sp + 4)  = acc[0][1];
        *(f32x4*)(sp + 8)  = acc[1][0];
        *(f32x4*)(sp + 12) = acc[1][1];
        sp[16] = fsumT[0];
        sp[17] = fsumT[1];
    }
    __syncthreads();
    if (wvi == 1) return;

    {
        const float* sp = accS + lane * 20;
        acc[0][0] += *(const f32x4*)(sp + 0);
        acc[0][1] += *(const f32x4*)(sp + 4);
        acc[1][0] += *(const f32x4*)(sp + 8);
        acc[1][1] += *(const f32x4*)(sp + 12);
        fsumT[0] += sp[16];
        fsumT[1] += sp[17];
    }
    float inv[2] = {1.0f / fsumT[0], 1.0f / fsumT[1]};

    // ---- epilogue: normalize (lane-uniform inv), head-sum over l15&3 ----
#pragma unroll
    for (int Mt = 0; Mt < 2; ++Mt)
#pragma unroll
        for (int ct = 0; ct < 2; ++ct) {
            float v[4];
#pragma unroll
            for (int r = 0; r < 4; ++r) {
                v[r] = acc[ct][Mt][r] * inv[Mt];
                v[r] += __shfl_xor(v[r], 1);
                v[r] += __shfl_xor(v[r], 2);
            }
            if ((l15 & 3) == 0) {
                int g = Mt * 4 + (l15 >> 2);
                float4 o4 = {v[0], v[1], v[2], v[3]};
                *(float4*)(out + ((((size_t)(b * 8 + g) * 32 + x) * 32 + y) << 5) +
                           ct * 16 + quad * 4) = o4;
            }
        }
}

// ---------------------------------------------------------------------------
extern "C" void kernel_launch(void* const* d_in, const int* in_sizes, int n_in,
                              void* d_out, int out_size, void* d_ws, size_t ws_size,
                              hipStream_t stream) {
    const float* x     = (const float*)d_in[0];
    const float* wq    = (const float*)d_in[1];
    const float* bq    = (const float*)d_in[2];
    const float* wk    = (const float*)d_in[3];
    const float* bk    = (const float*)d_in[4];
    const float* wv    = (const float*)d_in[5];
    const float* bv    = (const float*)d_in[6];
    const float* rel_h = (const float*)d_in[7];
    const float* rel_w = (const float*)d_in[8];
    float* out = (float*)d_out;

    // ws layout (bytes):
    //   Qb  f16 : 4096*1024*2            = 8,388,608
    //   Kb  f16 : 4*8*38*38*32*2         = 2,957,312
    //   V4  bf16: 4 shifts * 12160*128*2 = 12,451,840
    //   relp f16: 448*32*2               = 28,672
    unsigned char* ws = (unsigned char*)d_ws;
    f16*    Qb   = (f16*)ws;
    f16*    Kb   = (f16*)(ws + 8388608);
    __bf16* V4   = (__bf16*)(ws + 8388608 + 2957312);
    f16*    relp = (f16*)(ws + 8388608 + 2957312 + 12451840);

    hipLaunchKernelGGL(produce_kernel, dim3(1217), dim3(256), 0, stream,
                       x, wq, bq, wk, bk, wv, bv, rel_h, rel_w, Qb, Kb, V4, relp);
    hipLaunchKernelGGL(attn_kernel, dim3(4096), dim3(128), 0, stream,
                       Qb, Kb, V4, relp, out);
}